// Round 9
// baseline (2078.816 us; speedup 1.0000x reference)
//
#include <hip/hip_runtime.h>
#include <hip/hip_cooperative_groups.h>

namespace cg = cooperative_groups;

// Problem constants (fixed by the reference)
#define N 2048
#define D 256
#define C 768          // 3*D
#define V 2
#define L 16
#define NSTATE 15      // S_0..S_14 (step-15 mask provably empty)
#define NAPP 14        // encoder applications
#define TCAP 256       // canonical masked-entry cap per variant (expected ~107)
#define FCAP 64        // follower cap per step (expected ~32)
#define CHAIN_BLOCKS 512   // 2 blocks/CU — safely under cooperative grid limit

typedef __attribute__((ext_vector_type(8))) short bf16x8;
typedef __attribute__((ext_vector_type(4))) float f32x4;

__device__ __forceinline__ ushort bf16_rn(float x) {
  unsigned u = __float_as_uint(x);
  u += 0x7FFFu + ((u >> 16) & 1u);
  return (ushort)(u >> 16);
}
__device__ __forceinline__ float bf16_f(ushort h) {
  return __uint_as_float(((unsigned)h) << 16);
}

// Chunk-tiled operand layouts (chunk = 32 rows x 64 k = 2048 ushorts = 4 KB).
__device__ __forceinline__ size_t a_addr(int row, int k) {
  return ((size_t)(row >> 5) * 4 + (k >> 6)) * 2048 + (row & 31) * 64 + (k & 63);
}
__device__ __forceinline__ size_t wt_addr(int n, int k) {
  return ((size_t)(n >> 5) * 4 + (k >> 6)) * 2048 + (n & 31) * 64 + (k & 63);
}

// ---------------------------------------------------------------------------
// k_init: states0 = emb; A0 bf16 split (chunked); Wt=[W_self|W_nbr]^T split
// (chunked); zero out / fillpos.
// ---------------------------------------------------------------------------
__global__ __launch_bounds__(256) void k_init(
    const float* __restrict__ emb, const float* __restrict__ Ws,
    const float* __restrict__ Wn, float* __restrict__ states0,
    ushort* __restrict__ WtHi, ushort* __restrict__ WtLo,
    ushort* __restrict__ A0hi, ushort* __restrict__ A0lo,
    float* __restrict__ out, int* __restrict__ fillpos) {
  size_t i = (size_t)blockIdx.x * 256 + threadIdx.x;
  size_t stride = (size_t)gridDim.x * 256;
  for (size_t x = i; x < (size_t)N * D; x += stride) {
    float v = emb[x];
    states0[x] = v;
    ushort h = bf16_rn(v);
    ushort l = bf16_rn(v - bf16_f(h));
    size_t a = a_addr((int)(x >> 8), (int)(x & 255));
    A0hi[a] = h;
    A0lo[a] = l;
  }
  for (size_t x = i; x < (size_t)512 * 256; x += stride) {
    int n = (int)(x >> 8), k = (int)(x & 255);
    float v = (n < 256) ? Ws[(size_t)k * 256 + n] : Wn[(size_t)k * 256 + (n - 256)];
    ushort h = bf16_rn(v);
    size_t a = wt_addr(n, k);
    WtHi[a] = h;
    WtLo[a] = bf16_rn(v - bf16_f(h));
  }
  for (size_t x = i; x < (size_t)N * C; x += stride) out[x] = 0.f;
  for (size_t x = i; x < N; x += stride) fillpos[x] = 0;
}

// ---------------------------------------------------------------------------
// k_degA: fused k_deg (blocks 0..127) + k_metaA (blocks 128..159).
// ---------------------------------------------------------------------------
__global__ __launch_bounds__(256) void k_degA(
    const int* __restrict__ ei, int E, int* __restrict__ fillpos,
    const int* __restrict__ adj, const int* __restrict__ variants,
    int* __restrict__ stepP, int* __restrict__ stepDm,
    int* __restrict__ stepCnt, int* __restrict__ hasG, int* __restrict__ tlG) {
  __shared__ int tl_sh[16];
  __shared__ int foll[FCAP], fbits[FCAP];
  __shared__ int sh_tc, sh_fcnt, sh_ecnt;
  int t = threadIdx.x;
  if (blockIdx.x < 128) {
    for (int e = blockIdx.x * 256 + t; e < E; e += 128 * 256)
      atomicAdd(&fillpos[ei[E + e]], 1);
    return;
  }
  int vi = blockIdx.x - 128;
  int v = vi / L, i = vi % L;
  int a = variants[vi];
  if (t == 0) {
    int cnt = 0;
    for (int j = i + 1; j < L; j++) {
      int x = variants[v * L + j];
      bool dup = false;
      for (int q = 0; q < cnt; q++) if (tl_sh[q] == x) dup = true;
      if (!dup) tl_sh[cnt++] = x;
    }
    sh_tc = cnt;
    sh_fcnt = 0;
    sh_ecnt = 0;
    for (int q = 0; q < cnt; q++) tlG[vi * 16 + q] = tl_sh[q];
  }
  __syncthreads();
  for (int p = t; p < N; p += 256) {
    if (adj[(size_t)a * N + p] != 0) {
      int f = atomicAdd(&sh_fcnt, 1);
      if (f < FCAP) foll[f] = p;
    }
  }
  __syncthreads();
  int fc = sh_fcnt < FCAP ? sh_fcnt : FCAP;
  int tc = sh_tc;
  for (int x = t; x < fc; x += 256) fbits[x] = 0;
  __syncthreads();
  for (int x = t; x < fc * tc; x += 256) {
    int fi = x / tc, q = x - fi * tc;
    if (adj[(size_t)foll[fi] * N + tl_sh[q]] != 0) atomicOr(&fbits[fi], 1 << q);
  }
  __syncthreads();
  for (int fi = t; fi < fc; fi += 256) {
    int bits = fbits[fi];
    if (bits) {
      int e = atomicAdd(&sh_ecnt, 1);
      stepP[vi * FCAP + e] = foll[fi];
      stepDm[vi * FCAP + e] = bits;
    }
  }
  __syncthreads();
  if (t == 0) {
    stepCnt[vi] = sh_ecnt;
    hasG[vi] = (sh_fcnt > 0);
  }
}

// ---------------------------------------------------------------------------
// k_scan: exclusive prefix over degrees -> row_ptr; resets fillpos to starts.
// ---------------------------------------------------------------------------
__global__ __launch_bounds__(256) void k_scan(int* __restrict__ fillpos,
                                              int* __restrict__ row_ptr) {
  __shared__ int part[256];
  __shared__ int base[257];
  int t = threadIdx.x;
  int v[8];
  int s = 0;
  for (int j = 0; j < 8; j++) { v[j] = fillpos[t * 8 + j]; s += v[j]; }
  part[t] = s;
  __syncthreads();
  if (t == 0) {
    int acc = 0;
    for (int q = 0; q < 256; q++) { base[q] = acc; acc += part[q]; }
    base[256] = acc;
  }
  __syncthreads();
  int acc = base[t];
  for (int j = 0; j < 8; j++) {
    row_ptr[t * 8 + j] = acc;
    fillpos[t * 8 + j] = acc;
    acc += v[j];
  }
  if (t == 255) row_ptr[N] = base[256];
}

// ---------------------------------------------------------------------------
// k_fillB: fused k_fill (blocks 0..127) + k_metaB (blocks 128..128+V-1).
// ---------------------------------------------------------------------------
__global__ __launch_bounds__(256) void k_fillB(
    const int* __restrict__ ei, int E, int* __restrict__ fillpos,
    int* __restrict__ csr_src,
    const int* __restrict__ stepP, const int* __restrict__ stepDm,
    const int* __restrict__ stepCnt, const int* __restrict__ hasG,
    int* __restrict__ entP, int* __restrict__ entPrev, int* __restrict__ entDm,
    int* __restrict__ offsG, int* __restrict__ kidxG, int* __restrict__ cmatG,
    int* __restrict__ lastPG, int* __restrict__ lastIG, int* __restrict__ lastMG,
    int* __restrict__ cntG) {
  __shared__ int pmask[N];
  __shared__ int sP[16][FCAP];
  __shared__ int sDm[16][FCAP];
  __shared__ int cnt[16], offs[17];
  __shared__ int cmat_sh[256];
  __shared__ int sh_u;
  int t = threadIdx.x;
  if (blockIdx.x < 128) {
    for (int e = blockIdx.x * 256 + t; e < E; e += 128 * 256) {
      int dst = ei[E + e];
      int pos = atomicAdd(&fillpos[dst], 1);
      csr_src[pos] = ei[e];
    }
    return;
  }
  int v = blockIdx.x - 128;
  for (int p = t; p < N; p += 256) pmask[p] = 0;
  for (int x = t; x < 256; x += 256) cmat_sh[x] = 0;
  if (t < 16) cnt[t] = stepCnt[v * L + t];
  if (t == 0) sh_u = 0;
  __syncthreads();
  if (t == 0) {
    int acc = 0;
    for (int i = 0; i < 16; i++) {
      offs[i] = acc < TCAP ? acc : TCAP;
      acc += cnt[i];
    }
    offs[16] = acc < TCAP ? acc : TCAP;
    cntG[v * 2 + 0] = offs[16];
    int k = 0;
    for (int i = 0; i < L; i++) {
      kidxG[v * 16 + i] = k;
      if (hasG[v * L + i]) k++;
    }
  }
  for (int x = t; x < 16 * FCAP; x += 256) {
    int i = x >> 6, f = x & 63;
    if (f < stepCnt[v * L + i]) {
      int p = stepP[(v * L + i) * FCAP + f];
      sP[i][f] = p;
      sDm[i][f] = stepDm[(v * L + i) * FCAP + f];
      atomicOr(&pmask[p], 1 << i);
    }
  }
  __syncthreads();
  for (int x = t; x < 16 * FCAP; x += 256) {
    int i = x >> 6, f = x & 63;
    if (f < cnt[i]) {
      int e = offs[i] + f;
      if (e < TCAP) {
        int p = sP[i][f];
        entP[v * TCAP + e] = p;
        entDm[v * TCAP + e] = sDm[i][f];
        int m = pmask[p] & ((1 << i) - 1);
        int prev = -1;
        if (m) {
          int j = 31 - __clz(m);
          int cj = cnt[j];
          for (int f2 = 0; f2 < cj; f2++)
            if (sP[j][f2] == p) { prev = offs[j] + f2; break; }
        }
        entPrev[v * TCAP + e] = prev;
      }
    }
  }
  __syncthreads();
  for (int p = t; p < N; p += 256) {
    int m = pmask[p];
    if (m) {
      int u = atomicAdd(&sh_u, 1);
      int j = 31 - __clz(m);
      int li = -1;
      int cj = cnt[j];
      for (int f2 = 0; f2 < cj; f2++)
        if (sP[j][f2] == p) { li = offs[j] + f2; break; }
      lastPG[v * TCAP + u] = p;
      lastIG[v * TCAP + u] = li;
      lastMG[v * TCAP + u] = m;
      int mm = m;
      while (mm) {
        int bi = __ffs(mm) - 1; mm &= mm - 1;
        int m2 = m & ((1 << bi) - 1);
        while (m2) {
          int bj = __ffs(m2) - 1; m2 &= m2 - 1;
          atomicAdd(&cmat_sh[bi * 16 + bj], 1);
        }
      }
    }
  }
  __syncthreads();
  if (t == 0) cntG[v * 2 + 1] = sh_u;
  for (int x = t; x < 256; x += 256) cmatG[v * 256 + x] = cmat_sh[x];
  for (int x = t; x < 17; x += 256) offsG[v * 17 + x] = offs[x];
}

// ---------------------------------------------------------------------------
// k_chain: all 14 apps in ONE cooperative kernel, 2 grid.syncs per app.
// 512 blocks x 256 thr (2 blocks/CU, 8 waves/CU) — safely under the
// cooperative co-residency limit (R8's 1024 exceeded it and never launched).
// Phase G: grid-stride over 1024 Z-tiles (2/block), R4-validated gemm body.
// Phase C: one wave per row (row = b*4+wave), R7-validated comb body (no LDS).
// ---------------------------------------------------------------------------
__global__ __launch_bounds__(256) void k_chain(
    ushort* __restrict__ A0h, ushort* __restrict__ A0l,
    ushort* __restrict__ A1h, ushort* __restrict__ A1l,
    const ushort* __restrict__ WtHi, const ushort* __restrict__ WtLo,
    const float* __restrict__ bias, float* __restrict__ states,
    float* __restrict__ Z, const int* __restrict__ row_ptr,
    const int* __restrict__ csr_src) {
  __shared__ __align__(16) ushort Ash[32][72], Asl[32][72];
  __shared__ __align__(16) ushort Wsh[32][72], Wsl[32][72];
  cg::grid_group grid = cg::this_grid();
  const int tid = threadIdx.x, b = blockIdx.x;
  const int wave = tid >> 6, lane = tid & 63;
  const int quad = lane >> 4, l16 = lane & 15;
  const int wr = wave >> 1, wc = wave & 1;
  const int sr = tid >> 3, sc = (tid & 7) * 8;
  ushort* AH[2] = {A0h, A1h};
  ushort* AL[2] = {A0l, A1l};

  for (int s = 0; s < NAPP; s++) {
    const ushort* Ah = AH[s & 1];
    const ushort* Al = AL[s & 1];
    ushort* Nh = AH[(s + 1) & 1];
    ushort* Nl = AL[(s + 1) & 1];
    float* stnext = states + (size_t)(s + 1) * N * D;

    // ---- phase G: Z = A @ Wt (bf16 3-product split, fp32 accum) ----
    for (int tile = b; tile < 1024; tile += CHAIN_BLOCKS) {
      const int mb = tile >> 4, nb = tile & 15;
      f32x4 acc = {0.f, 0.f, 0.f, 0.f};
      size_t abase = (size_t)mb * 4 * 2048 + (size_t)tid * 8;
      size_t wbase = (size_t)nb * 4 * 2048 + (size_t)tid * 8;
      uint4 ra  = *(const uint4*)&Ah[abase];
      uint4 rl  = *(const uint4*)&Al[abase];
      uint4 rwh = *(const uint4*)&WtHi[wbase];
      uint4 rwl = *(const uint4*)&WtLo[wbase];
#pragma unroll
      for (int c = 0; c < 4; c++) {
        *(uint4*)&Ash[sr][sc] = ra;
        *(uint4*)&Asl[sr][sc] = rl;
        *(uint4*)&Wsh[sr][sc] = rwh;
        *(uint4*)&Wsl[sr][sc] = rwl;
        __syncthreads();
        if (c < 3) {
          size_t o = (size_t)(c + 1) * 2048;
          ra  = *(const uint4*)&Ah[abase + o];
          rl  = *(const uint4*)&Al[abase + o];
          rwh = *(const uint4*)&WtHi[wbase + o];
          rwl = *(const uint4*)&WtLo[wbase + o];
        }
#pragma unroll
        for (int kf = 0; kf < 2; kf++) {
          int ko = kf * 32 + quad * 8;
          bf16x8 a_h = *(const bf16x8*)&Ash[wr * 16 + l16][ko];
          bf16x8 a_l = *(const bf16x8*)&Asl[wr * 16 + l16][ko];
          bf16x8 w_h = *(const bf16x8*)&Wsh[wc * 16 + l16][ko];
          bf16x8 w_l = *(const bf16x8*)&Wsl[wc * 16 + l16][ko];
          acc = __builtin_amdgcn_mfma_f32_16x16x32_bf16(a_h, w_h, acc, 0, 0, 0);
          acc = __builtin_amdgcn_mfma_f32_16x16x32_bf16(a_h, w_l, acc, 0, 0, 0);
          acc = __builtin_amdgcn_mfma_f32_16x16x32_bf16(a_l, w_h, acc, 0, 0, 0);
        }
        __syncthreads();
      }
      int col = nb * 32 + wc * 16 + l16;
      int row0 = mb * 32 + wr * 16 + quad * 4;
#pragma unroll
      for (int r = 0; r < 4; r++)
        Z[(size_t)(row0 + r) * 512 + col] = acc[r];
    }
    grid.sync();   // Z complete & visible

    // ---- phase C: next = relu(Z1 + S.Z2 + b); one wave per row ----
    {
      int row = b * 4 + wave;
      const float4* Zp = (const float4*)Z;
      float4 acc = Zp[(size_t)row * 128 + lane];       // Z1 self
      float4 acc2 = {0.f, 0.f, 0.f, 0.f};
      int e0 = row_ptr[row], e1 = row_ptr[row + 1];
      int e = e0;
      for (; e + 1 < e1; e += 2) {
        int s0 = csr_src[e], s1 = csr_src[e + 1];
        float4 x0 = Zp[(size_t)s0 * 128 + 64 + lane];
        float4 x1 = Zp[(size_t)s1 * 128 + 64 + lane];
        acc.x += x0.x; acc.y += x0.y; acc.z += x0.z; acc.w += x0.w;
        acc2.x += x1.x; acc2.y += x1.y; acc2.z += x1.z; acc2.w += x1.w;
      }
      if (e < e1) {
        float4 x0 = Zp[(size_t)csr_src[e] * 128 + 64 + lane];
        acc.x += x0.x; acc.y += x0.y; acc.z += x0.z; acc.w += x0.w;
      }
      float4 bv = ((const float4*)bias)[lane];
      float v0 = fmaxf(acc.x + acc2.x + bv.x, 0.f);
      float v1 = fmaxf(acc.y + acc2.y + bv.y, 0.f);
      float v2 = fmaxf(acc.z + acc2.z + bv.z, 0.f);
      float v3 = fmaxf(acc.w + acc2.w + bv.w, 0.f);
      *(float4*)(stnext + (size_t)row * D + lane * 4) =
          make_float4(v0, v1, v2, v3);
      ushort h0 = bf16_rn(v0), h1 = bf16_rn(v1), h2 = bf16_rn(v2), h3 = bf16_rn(v3);
      size_t ca = a_addr(row, lane * 4);
      *(ushort4*)&Nh[ca] = make_ushort4(h0, h1, h2, h3);
      *(ushort4*)&Nl[ca] = make_ushort4(
          bf16_rn(v0 - bf16_f(h0)), bf16_rn(v1 - bf16_f(h1)),
          bf16_rn(v2 - bf16_f(h2)), bf16_rn(v3 - bf16_f(h3)));
    }
    grid.sync();   // states[s+1] / A[s+1] visible
  }
}

// ---------------------------------------------------------------------------
// k_pi: LINEAR reformulation (validated R5-R7).
// ---------------------------------------------------------------------------
#define PI_LDS_BYTES (TCAP * 64 * 4 + 16 * 64 * 4 + 3 * TCAP * 4 + 17 * 4 + 16 * 4 + 256 * 4)
__global__ __launch_bounds__(64) void k_pi(
    const float* __restrict__ states, float* __restrict__ out,
    const int* __restrict__ variants,
    const int* __restrict__ entP, const int* __restrict__ entPrev,
    const int* __restrict__ entDm, const int* __restrict__ offsG,
    const int* __restrict__ kidxG, const int* __restrict__ tlG,
    const int* __restrict__ cmatG, const int* __restrict__ lastPG,
    const int* __restrict__ lastIG, const int* __restrict__ lastMG,
    const int* __restrict__ cntG) {
  extern __shared__ __align__(16) float smf[];
  float* catb = smf;
  float* S_lds = catb + TCAP * 64;
  int* eP  = (int*)(S_lds + 16 * 64);
  int* ePr = eP + TCAP;
  int* eDm = ePr + TCAP;
  int* offs = eDm + TCAP;
  int* kidx = offs + 17;
  int* tl = kidx + 16;
  int v = blockIdx.x / 12, cgi = blockIdx.x % 12;
  int grp = cgi >> 2;
  int lane = threadIdx.x;
  int cl = (cgi & 3) * 64 + lane;
  int col = cgi * 64 + lane;

  int T = cntG[v * 2 + 0], U = cntG[v * 2 + 1];
  for (int x = lane; x < T; x += 64) {
    eP[x] = entP[v * TCAP + x];
    ePr[x] = entPrev[v * TCAP + x];
    eDm[x] = entDm[v * TCAP + x];
  }
  for (int x = lane; x < 17; x += 64) offs[x] = offsG[v * 17 + x];
  if (lane < 16) kidx[lane] = kidxG[v * 16 + lane];
  for (int x = lane; x < 256; x += 64) tl[x] = tlG[v * 256 + x];
  __syncthreads();

  for (int i = 0; i < L; i++) {
    int kk = kidx[i]; if (kk > NSTATE - 1) kk = NSTATE - 1;
    const float* embS = states + (size_t)kk * N * D;
    int o0 = offs[i], o1 = offs[i + 1];
    if (grp == 0) {
      for (int e = o0; e < o1; e++)
        catb[e * 64 + lane] = embS[(size_t)eP[e] * D + cl];
    } else if (grp == 1) {
      float embA = embS[(size_t)variants[v * L + i] * D + cl];
      for (int e = o0; e < o1; e++) catb[e * 64 + lane] = embA;
    } else {
      for (int e = o0; e < o1; e++) {
        float s = 0.f;
        int b = eDm[e];
        while (b) {
          int q = __ffs(b) - 1; b &= b - 1;
          s += embS[(size_t)tl[i * 16 + q] * D + cl];
        }
        catb[e * 64 + lane] = s;
      }
    }
  }
  for (int e = 0; e < T; e++) {
    int pr = ePr[e];
    if (pr >= 0) catb[e * 64 + lane] += catb[pr * 64 + lane];
  }
  float S[16];
  float Sp = 0.f;
#pragma unroll
  for (int i = 0; i < 16; i++) {
    float a = 0.f;
    for (int e = offs[i]; e < offs[i + 1]; e++) a += catb[e * 64 + lane];
    float s = Sp + a;
#pragma unroll
    for (int j = 0; j < 16; j++)
      if (j < i) s += (float)cmatG[v * 256 + i * 16 + j] * S[j];
    S[i] = s;
    S_lds[i * 64 + lane] = s;
    Sp = s;
  }
  for (int u = 0; u < U; u++) {
    int p = lastPG[v * TCAP + u];
    int li = lastIG[v * TCAP + u];
    int m = lastMG[v * TCAP + u];
    float acc = catb[li * 64 + lane];
    while (m) {
      int q = __ffs(m) - 1; m &= m - 1;
      acc += S_lds[q * 64 + lane];
    }
    atomicAdd(&out[(size_t)p * C + col], acc);
  }
}

// ---------------------------------------------------------------------------
extern "C" void kernel_launch(void* const* d_in, const int* in_sizes, int n_in,
                              void* d_out, int out_size, void* d_ws, size_t ws_size,
                              hipStream_t stream) {
  const float* emb      = (const float*)d_in[0];
  const float* Ws       = (const float*)d_in[1];
  const float* Wn       = (const float*)d_in[2];
  const float* bias     = (const float*)d_in[3];
  const int*   variants = (const int*)d_in[4];
  const int*   adj      = (const int*)d_in[5];
  const int*   ei       = (const int*)d_in[6];
  const int    E        = in_sizes[6] / 2;
  float* out            = (float*)d_out;

  char* base = (char*)d_ws;
  float* states = (float*)base;            base += (size_t)NSTATE * N * D * 4;
  float* Z      = (float*)base;            base += (size_t)N * 512 * 4;
  ushort* WtHi  = (ushort*)base;           base += (size_t)512 * 256 * 2;
  ushort* WtLo  = (ushort*)base;           base += (size_t)512 * 256 * 2;
  ushort* A0h   = (ushort*)base;           base += (size_t)N * D * 2;
  ushort* A0l   = (ushort*)base;           base += (size_t)N * D * 2;
  ushort* A1h   = (ushort*)base;           base += (size_t)N * D * 2;
  ushort* A1l   = (ushort*)base;           base += (size_t)N * D * 2;
  int* row_ptr  = (int*)base;              base += (N + 1) * 4;
  int* fillpos  = (int*)base;              base += N * 4;
  int* csr_src  = (int*)base;              base += (size_t)E * 4;
  int* stepP    = (int*)base;              base += V * L * FCAP * 4;
  int* stepDm   = (int*)base;              base += V * L * FCAP * 4;
  int* stepCnt  = (int*)base;              base += V * L * 4;
  int* hasG     = (int*)base;              base += V * L * 4;
  int* entP     = (int*)base;              base += V * TCAP * 4;
  int* entPrev  = (int*)base;              base += V * TCAP * 4;
  int* entDm    = (int*)base;              base += V * TCAP * 4;
  int* offsG    = (int*)base;              base += V * 17 * 4;
  int* kidxG    = (int*)base;              base += V * 16 * 4;
  int* tlG      = (int*)base;              base += V * 256 * 4;
  int* cmatG    = (int*)base;              base += V * 256 * 4;
  int* lastPG   = (int*)base;              base += V * TCAP * 4;
  int* lastIG   = (int*)base;              base += V * TCAP * 4;
  int* lastMG   = (int*)base;              base += V * TCAP * 4;
  int* cntG     = (int*)base;              base += V * 2 * 4;

  hipFuncSetAttribute((const void*)k_pi,
                      hipFuncAttributeMaxDynamicSharedMemorySize, PI_LDS_BYTES);

  k_init<<<512, 256, 0, stream>>>(emb, Ws, Wn, states, WtHi, WtLo, A0h, A0l,
                                  out, fillpos);
  k_degA<<<128 + V * L, 256, 0, stream>>>(ei, E, fillpos, adj, variants,
                                          stepP, stepDm, stepCnt, hasG, tlG);
  k_scan<<<1, 256, 0, stream>>>(fillpos, row_ptr);
  k_fillB<<<128 + V, 256, 0, stream>>>(ei, E, fillpos, csr_src, stepP, stepDm,
                                       stepCnt, hasG, entP, entPrev, entDm,
                                       offsG, kidxG, cmatG, lastPG, lastIG,
                                       lastMG, cntG);
  {
    void* args[] = {(void*)&A0h, (void*)&A0l, (void*)&A1h, (void*)&A1l,
                    (void*)&WtHi, (void*)&WtLo, (void*)&bias, (void*)&states,
                    (void*)&Z, (void*)&row_ptr, (void*)&csr_src};
    hipLaunchCooperativeKernel((const void*)k_chain, dim3(CHAIN_BLOCKS),
                               dim3(256), args, 0, stream);
  }
  k_pi<<<V * 12, 64, PI_LDS_BYTES, stream>>>(states, out, variants, entP,
                                             entPrev, entDm, offsG, kidxG, tlG,
                                             cmatG, lastPG, lastIG, lastMG, cntG);
}

// Round 10
// 457.335 us; speedup vs baseline: 4.5455x; 4.5455x over previous
//
#include <hip/hip_runtime.h>

// Problem constants (fixed by the reference)
#define N 2048
#define D 256
#define C 768          // 3*D
#define V 2
#define L 16
#define NSTATE 15      // S_0..S_14 (step-15 mask provably empty)
#define NAPP 14        // encoder applications
#define TCAP 256       // canonical masked-entry cap per variant (expected ~107)
#define FCAP 64        // follower cap per step (expected ~32)

typedef __attribute__((ext_vector_type(8))) short bf16x8;
typedef __attribute__((ext_vector_type(4))) float f32x4;

__device__ __forceinline__ ushort bf16_rn(float x) {
  unsigned u = __float_as_uint(x);
  u += 0x7FFFu + ((u >> 16) & 1u);
  return (ushort)(u >> 16);
}
__device__ __forceinline__ float bf16_f(ushort h) {
  return __uint_as_float(((unsigned)h) << 16);
}

// Chunk-tiled operand layouts (chunk = 32 rows x 64 k = 2048 ushorts = 4 KB).
__device__ __forceinline__ size_t a_addr(int row, int k) {
  return ((size_t)(row >> 5) * 4 + (k >> 6)) * 2048 + (row & 31) * 64 + (k & 63);
}
__device__ __forceinline__ size_t wt_addr(int n, int k) {
  return ((size_t)(n >> 5) * 4 + (k >> 6)) * 2048 + (n & 31) * 64 + (k & 63);
}

// ---------------------------------------------------------------------------
// k_init: states0 = emb; A0 bf16 split (chunked); Wt=[W_self|W_nbr]^T split
// (chunked); zero out / fillpos.
// ---------------------------------------------------------------------------
__global__ __launch_bounds__(256) void k_init(
    const float* __restrict__ emb, const float* __restrict__ Ws,
    const float* __restrict__ Wn, float* __restrict__ states0,
    ushort* __restrict__ WtHi, ushort* __restrict__ WtLo,
    ushort* __restrict__ A0hi, ushort* __restrict__ A0lo,
    float* __restrict__ out, int* __restrict__ fillpos) {
  size_t i = (size_t)blockIdx.x * 256 + threadIdx.x;
  size_t stride = (size_t)gridDim.x * 256;
  for (size_t x = i; x < (size_t)N * D; x += stride) {
    float v = emb[x];
    states0[x] = v;
    ushort h = bf16_rn(v);
    ushort l = bf16_rn(v - bf16_f(h));
    size_t a = a_addr((int)(x >> 8), (int)(x & 255));
    A0hi[a] = h;
    A0lo[a] = l;
  }
  for (size_t x = i; x < (size_t)512 * 256; x += stride) {
    int n = (int)(x >> 8), k = (int)(x & 255);
    float v = (n < 256) ? Ws[(size_t)k * 256 + n] : Wn[(size_t)k * 256 + (n - 256)];
    ushort h = bf16_rn(v);
    size_t a = wt_addr(n, k);
    WtHi[a] = h;
    WtLo[a] = bf16_rn(v - bf16_f(h));
  }
  for (size_t x = i; x < (size_t)N * C; x += stride) out[x] = 0.f;
  for (size_t x = i; x < N; x += stride) fillpos[x] = 0;
}

// ---------------------------------------------------------------------------
// k_degA: fused k_deg (blocks 0..127) + k_metaA (blocks 128..159).
// ---------------------------------------------------------------------------
__global__ __launch_bounds__(256) void k_degA(
    const int* __restrict__ ei, int E, int* __restrict__ fillpos,
    const int* __restrict__ adj, const int* __restrict__ variants,
    int* __restrict__ stepP, int* __restrict__ stepDm,
    int* __restrict__ stepCnt, int* __restrict__ hasG, int* __restrict__ tlG) {
  __shared__ int tl_sh[16];
  __shared__ int foll[FCAP], fbits[FCAP];
  __shared__ int sh_tc, sh_fcnt, sh_ecnt;
  int t = threadIdx.x;
  if (blockIdx.x < 128) {
    for (int e = blockIdx.x * 256 + t; e < E; e += 128 * 256)
      atomicAdd(&fillpos[ei[E + e]], 1);
    return;
  }
  int vi = blockIdx.x - 128;
  int v = vi / L, i = vi % L;
  int a = variants[vi];
  if (t == 0) {
    int cnt = 0;
    for (int j = i + 1; j < L; j++) {
      int x = variants[v * L + j];
      bool dup = false;
      for (int q = 0; q < cnt; q++) if (tl_sh[q] == x) dup = true;
      if (!dup) tl_sh[cnt++] = x;
    }
    sh_tc = cnt;
    sh_fcnt = 0;
    sh_ecnt = 0;
    for (int q = 0; q < cnt; q++) tlG[vi * 16 + q] = tl_sh[q];
  }
  __syncthreads();
  for (int p = t; p < N; p += 256) {
    if (adj[(size_t)a * N + p] != 0) {
      int f = atomicAdd(&sh_fcnt, 1);
      if (f < FCAP) foll[f] = p;
    }
  }
  __syncthreads();
  int fc = sh_fcnt < FCAP ? sh_fcnt : FCAP;
  int tc = sh_tc;
  for (int x = t; x < fc; x += 256) fbits[x] = 0;
  __syncthreads();
  for (int x = t; x < fc * tc; x += 256) {
    int fi = x / tc, q = x - fi * tc;
    if (adj[(size_t)foll[fi] * N + tl_sh[q]] != 0) atomicOr(&fbits[fi], 1 << q);
  }
  __syncthreads();
  for (int fi = t; fi < fc; fi += 256) {
    int bits = fbits[fi];
    if (bits) {
      int e = atomicAdd(&sh_ecnt, 1);
      stepP[vi * FCAP + e] = foll[fi];
      stepDm[vi * FCAP + e] = bits;
    }
  }
  __syncthreads();
  if (t == 0) {
    stepCnt[vi] = sh_ecnt;
    hasG[vi] = (sh_fcnt > 0);
  }
}

// ---------------------------------------------------------------------------
// k_scan: exclusive prefix over degrees -> row_ptr; resets fillpos to starts.
// ---------------------------------------------------------------------------
__global__ __launch_bounds__(256) void k_scan(int* __restrict__ fillpos,
                                              int* __restrict__ row_ptr) {
  __shared__ int part[256];
  __shared__ int base[257];
  int t = threadIdx.x;
  int v[8];
  int s = 0;
  for (int j = 0; j < 8; j++) { v[j] = fillpos[t * 8 + j]; s += v[j]; }
  part[t] = s;
  __syncthreads();
  if (t == 0) {
    int acc = 0;
    for (int q = 0; q < 256; q++) { base[q] = acc; acc += part[q]; }
    base[256] = acc;
  }
  __syncthreads();
  int acc = base[t];
  for (int j = 0; j < 8; j++) {
    row_ptr[t * 8 + j] = acc;
    fillpos[t * 8 + j] = acc;
    acc += v[j];
  }
  if (t == 255) row_ptr[N] = base[256];
}

// ---------------------------------------------------------------------------
// k_fillB: fused k_fill (blocks 0..127) + k_metaB (blocks 128..128+V-1).
// ---------------------------------------------------------------------------
__global__ __launch_bounds__(256) void k_fillB(
    const int* __restrict__ ei, int E, int* __restrict__ fillpos,
    int* __restrict__ csr_src,
    const int* __restrict__ stepP, const int* __restrict__ stepDm,
    const int* __restrict__ stepCnt, const int* __restrict__ hasG,
    int* __restrict__ entP, int* __restrict__ entPrev, int* __restrict__ entDm,
    int* __restrict__ offsG, int* __restrict__ kidxG, int* __restrict__ cmatG,
    int* __restrict__ lastPG, int* __restrict__ lastIG, int* __restrict__ lastMG,
    int* __restrict__ cntG) {
  __shared__ int pmask[N];
  __shared__ int sP[16][FCAP];
  __shared__ int sDm[16][FCAP];
  __shared__ int cnt[16], offs[17];
  __shared__ int cmat_sh[256];
  __shared__ int sh_u;
  int t = threadIdx.x;
  if (blockIdx.x < 128) {
    for (int e = blockIdx.x * 256 + t; e < E; e += 128 * 256) {
      int dst = ei[E + e];
      int pos = atomicAdd(&fillpos[dst], 1);
      csr_src[pos] = ei[e];
    }
    return;
  }
  int v = blockIdx.x - 128;
  for (int p = t; p < N; p += 256) pmask[p] = 0;
  for (int x = t; x < 256; x += 256) cmat_sh[x] = 0;
  if (t < 16) cnt[t] = stepCnt[v * L + t];
  if (t == 0) sh_u = 0;
  __syncthreads();
  if (t == 0) {
    int acc = 0;
    for (int i = 0; i < 16; i++) {
      offs[i] = acc < TCAP ? acc : TCAP;
      acc += cnt[i];
    }
    offs[16] = acc < TCAP ? acc : TCAP;
    cntG[v * 2 + 0] = offs[16];
    int k = 0;
    for (int i = 0; i < L; i++) {
      kidxG[v * 16 + i] = k;
      if (hasG[v * L + i]) k++;
    }
  }
  for (int x = t; x < 16 * FCAP; x += 256) {
    int i = x >> 6, f = x & 63;
    if (f < stepCnt[v * L + i]) {
      int p = stepP[(v * L + i) * FCAP + f];
      sP[i][f] = p;
      sDm[i][f] = stepDm[(v * L + i) * FCAP + f];
      atomicOr(&pmask[p], 1 << i);
    }
  }
  __syncthreads();
  for (int x = t; x < 16 * FCAP; x += 256) {
    int i = x >> 6, f = x & 63;
    if (f < cnt[i]) {
      int e = offs[i] + f;
      if (e < TCAP) {
        int p = sP[i][f];
        entP[v * TCAP + e] = p;
        entDm[v * TCAP + e] = sDm[i][f];
        int m = pmask[p] & ((1 << i) - 1);
        int prev = -1;
        if (m) {
          int j = 31 - __clz(m);
          int cj = cnt[j];
          for (int f2 = 0; f2 < cj; f2++)
            if (sP[j][f2] == p) { prev = offs[j] + f2; break; }
        }
        entPrev[v * TCAP + e] = prev;
      }
    }
  }
  __syncthreads();
  for (int p = t; p < N; p += 256) {
    int m = pmask[p];
    if (m) {
      int u = atomicAdd(&sh_u, 1);
      int j = 31 - __clz(m);
      int li = -1;
      int cj = cnt[j];
      for (int f2 = 0; f2 < cj; f2++)
        if (sP[j][f2] == p) { li = offs[j] + f2; break; }
      lastPG[v * TCAP + u] = p;
      lastIG[v * TCAP + u] = li;
      lastMG[v * TCAP + u] = m;
      int mm = m;
      while (mm) {
        int bi = __ffs(mm) - 1; mm &= mm - 1;
        int m2 = m & ((1 << bi) - 1);
        while (m2) {
          int bj = __ffs(m2) - 1; m2 &= m2 - 1;
          atomicAdd(&cmat_sh[bi * 16 + bj], 1);
        }
      }
    }
  }
  __syncthreads();
  if (t == 0) cntG[v * 2 + 1] = sh_u;
  for (int x = t; x < 256; x += 256) cmatG[v * 256 + x] = cmat_sh[x];
  for (int x = t; x < 17; x += 256) offsG[v * 17 + x] = offs[x];
}

// ---------------------------------------------------------------------------
// k_gemm: Z = A @ [W_self|W_nbr]  (M=2048, K=256, N=512), bf16 3-product
// split, fp32 accum, LDS double-buffered.  (R7-validated; used once for app 0)
// ---------------------------------------------------------------------------
__global__ __launch_bounds__(256) void k_gemm(
    const ushort* __restrict__ Ah, const ushort* __restrict__ Al,
    const ushort* __restrict__ Wh_g, const ushort* __restrict__ Wl_g,
    float* __restrict__ Z) {
  __shared__ __align__(16) ushort Ash[2][32][72], Asl[2][32][72];
  __shared__ __align__(16) ushort Wsh[2][32][72], Wsl[2][32][72];
  const int tid = threadIdx.x, wave = tid >> 6, lane = tid & 63;
  const int quad = lane >> 4, l16 = lane & 15;
  const int wr = wave >> 1, wc = wave & 1;
  const int mb = blockIdx.x, nb = blockIdx.y;
  const int sr = tid >> 3, sc = (tid & 7) * 8;

  f32x4 acc = {0.f, 0.f, 0.f, 0.f};
  size_t abase = (size_t)mb * 4 * 2048 + (size_t)tid * 8;
  size_t wbase = (size_t)nb * 4 * 2048 + (size_t)tid * 8;
  {
    uint4 ra  = *(const uint4*)&Ah[abase];
    uint4 rl  = *(const uint4*)&Al[abase];
    uint4 rwh = *(const uint4*)&Wh_g[wbase];
    uint4 rwl = *(const uint4*)&Wl_g[wbase];
    *(uint4*)&Ash[0][sr][sc] = ra;
    *(uint4*)&Asl[0][sr][sc] = rl;
    *(uint4*)&Wsh[0][sr][sc] = rwh;
    *(uint4*)&Wsl[0][sr][sc] = rwl;
  }
  __syncthreads();
#pragma unroll
  for (int c = 0; c < 4; c++) {
    const int rb = c & 1;
    uint4 ra, rl, rwh, rwl;
    if (c < 3) {
      size_t o = (size_t)(c + 1) * 2048;
      ra  = *(const uint4*)&Ah[abase + o];
      rl  = *(const uint4*)&Al[abase + o];
      rwh = *(const uint4*)&Wh_g[wbase + o];
      rwl = *(const uint4*)&Wl_g[wbase + o];
    }
#pragma unroll
    for (int kf = 0; kf < 2; kf++) {
      int ko = kf * 32 + quad * 8;
      bf16x8 a_h = *(const bf16x8*)&Ash[rb][wr * 16 + l16][ko];
      bf16x8 a_l = *(const bf16x8*)&Asl[rb][wr * 16 + l16][ko];
      bf16x8 w_h = *(const bf16x8*)&Wsh[rb][wc * 16 + l16][ko];
      bf16x8 w_l = *(const bf16x8*)&Wsl[rb][wc * 16 + l16][ko];
      acc = __builtin_amdgcn_mfma_f32_16x16x32_bf16(a_h, w_h, acc, 0, 0, 0);
      acc = __builtin_amdgcn_mfma_f32_16x16x32_bf16(a_h, w_l, acc, 0, 0, 0);
      acc = __builtin_amdgcn_mfma_f32_16x16x32_bf16(a_l, w_h, acc, 0, 0, 0);
    }
    if (c < 3) {
      const int wb = rb ^ 1;
      *(uint4*)&Ash[wb][sr][sc] = ra;
      *(uint4*)&Asl[wb][sr][sc] = rl;
      *(uint4*)&Wsh[wb][sr][sc] = rwh;
      *(uint4*)&Wsl[wb][sr][sc] = rwl;
      __syncthreads();
    }
  }
  int col = nb * 32 + wc * 16 + l16;
  int row0 = mb * 32 + wr * 16 + quad * 4;
#pragma unroll
  for (int r = 0; r < 4; r++)
    Z[(size_t)(row0 + r) * 512 + col] = acc[r];
}

// ---------------------------------------------------------------------------
// k_fused: comb of app s-1 + gemm of app s in ONE kernel (halves the chain's
// dependent-dispatch count).  Grid (128,4), block = 16-row x 128-col Z tile.
// Phase A: comb own 16 rows from Zprev (R7-validated gather body), bf16 split
// straight into LDS (A never round-trips global).  nb==0 writes states[s].
// Phase B: 16x128 GEMM, K=256 in 4 chunks; W strip staged per chunk.
// LDS pad: A stride 264 (2-way alias only), W stride 72 (2-way) — free (m136).
// ---------------------------------------------------------------------------
__global__ __launch_bounds__(256) void k_fused(
    const float* __restrict__ Zprev, float* __restrict__ Znext,
    const ushort* __restrict__ WtHi, const ushort* __restrict__ WtLo,
    const float* __restrict__ bias, const int* __restrict__ row_ptr,
    const int* __restrict__ csr_src, float* __restrict__ stthis) {
  __shared__ __align__(16) ushort Ash[16][264], Asl[16][264];
  __shared__ __align__(16) ushort Wsh[128][72], Wsl[128][72];
  const int tid = threadIdx.x, wave = tid >> 6, lane = tid & 63;
  const int quad = lane >> 4, l16 = lane & 15;
  const int mb = blockIdx.x, nb = blockIdx.y;
  const int r0 = mb * 16;

  // ---- phase A: comb rows r0..r0+15 (4 rows/wave) ----
  const float4* Zp = (const float4*)Zprev;
  float4 bv = ((const float4*)bias)[lane];
#pragma unroll
  for (int rr = 0; rr < 4; rr++) {
    int row = r0 + wave * 4 + rr;
    float4 acc = Zp[(size_t)row * 128 + lane];        // Z1 self
    float4 acc2 = {0.f, 0.f, 0.f, 0.f};
    int e0 = row_ptr[row], e1 = row_ptr[row + 1];
    int e = e0;
    for (; e + 1 < e1; e += 2) {
      int s0 = csr_src[e], s1 = csr_src[e + 1];
      float4 x0 = Zp[(size_t)s0 * 128 + 64 + lane];
      float4 x1 = Zp[(size_t)s1 * 128 + 64 + lane];
      acc.x += x0.x; acc.y += x0.y; acc.z += x0.z; acc.w += x0.w;
      acc2.x += x1.x; acc2.y += x1.y; acc2.z += x1.z; acc2.w += x1.w;
    }
    if (e < e1) {
      float4 x0 = Zp[(size_t)csr_src[e] * 128 + 64 + lane];
      acc.x += x0.x; acc.y += x0.y; acc.z += x0.z; acc.w += x0.w;
    }
    float v0 = fmaxf(acc.x + acc2.x + bv.x, 0.f);
    float v1 = fmaxf(acc.y + acc2.y + bv.y, 0.f);
    float v2 = fmaxf(acc.z + acc2.z + bv.z, 0.f);
    float v3 = fmaxf(acc.w + acc2.w + bv.w, 0.f);
    if (nb == 0)
      *(float4*)(stthis + (size_t)row * D + lane * 4) =
          make_float4(v0, v1, v2, v3);
    ushort h0 = bf16_rn(v0), h1 = bf16_rn(v1), h2 = bf16_rn(v2), h3 = bf16_rn(v3);
    int ar = wave * 4 + rr;
    *(ushort4*)&Ash[ar][lane * 4] = make_ushort4(h0, h1, h2, h3);
    *(ushort4*)&Asl[ar][lane * 4] = make_ushort4(
        bf16_rn(v0 - bf16_f(h0)), bf16_rn(v1 - bf16_f(h1)),
        bf16_rn(v2 - bf16_f(h2)), bf16_rn(v3 - bf16_f(h3)));
  }

  // ---- phase B: Znext tile = A(16x256) @ Wt strip (256x128) ----
  f32x4 acc[2] = {};
  const int swn = tid >> 3, swk = (tid & 7) * 8;
#pragma unroll
  for (int kc = 0; kc < 4; kc++) {
    __syncthreads();   // A ready (kc=0) / prior W reads done (kc>0)
#pragma unroll
    for (int sub = 0; sub < 4; sub++) {
      int n = nb * 128 + sub * 32;
      size_t gb = ((size_t)(n >> 5) * 4 + kc) * 2048 + (size_t)tid * 8;
      *(uint4*)&Wsh[sub * 32 + swn][swk] = *(const uint4*)&WtHi[gb];
      *(uint4*)&Wsl[sub * 32 + swn][swk] = *(const uint4*)&WtLo[gb];
    }
    __syncthreads();
#pragma unroll
    for (int kf = 0; kf < 2; kf++) {
      int ko = kc * 64 + kf * 32 + quad * 8;
      int wo = kf * 32 + quad * 8;
      bf16x8 a_h = *(const bf16x8*)&Ash[l16][ko];
      bf16x8 a_l = *(const bf16x8*)&Asl[l16][ko];
#pragma unroll
      for (int nt = 0; nt < 2; nt++) {
        bf16x8 w_h = *(const bf16x8*)&Wsh[wave * 32 + nt * 16 + l16][wo];
        bf16x8 w_l = *(const bf16x8*)&Wsl[wave * 32 + nt * 16 + l16][wo];
        acc[nt] = __builtin_amdgcn_mfma_f32_16x16x32_bf16(a_h, w_h, acc[nt], 0, 0, 0);
        acc[nt] = __builtin_amdgcn_mfma_f32_16x16x32_bf16(a_h, w_l, acc[nt], 0, 0, 0);
        acc[nt] = __builtin_amdgcn_mfma_f32_16x16x32_bf16(a_l, w_h, acc[nt], 0, 0, 0);
      }
    }
  }
#pragma unroll
  for (int nt = 0; nt < 2; nt++) {
    int col = nb * 128 + wave * 32 + nt * 16 + l16;
#pragma unroll
    for (int r = 0; r < 4; r++) {
      int row = r0 + quad * 4 + r;
      Znext[(size_t)row * 512 + col] = acc[nt][r];
    }
  }
}

// ---------------------------------------------------------------------------
// k_comb: final comb (app 13 -> states[14]).  R7-validated; NA writes are
// scratch here.
// ---------------------------------------------------------------------------
__global__ __launch_bounds__(256) void k_comb(
    const float* __restrict__ Z, const float* __restrict__ bias,
    const int* __restrict__ row_ptr, const int* __restrict__ csr_src,
    float* __restrict__ stnext, ushort* __restrict__ NAh,
    ushort* __restrict__ NAl) {
  int row = blockIdx.x * 4 + (threadIdx.x >> 6);
  int lane = threadIdx.x & 63;
  const float4* Zp = (const float4*)Z;
  float4 acc = Zp[(size_t)row * 128 + lane];
  float4 acc2 = {0.f, 0.f, 0.f, 0.f};
  int e0 = row_ptr[row], e1 = row_ptr[row + 1];
  int e = e0;
  for (; e + 1 < e1; e += 2) {
    int s0 = csr_src[e], s1 = csr_src[e + 1];
    float4 x0 = Zp[(size_t)s0 * 128 + 64 + lane];
    float4 x1 = Zp[(size_t)s1 * 128 + 64 + lane];
    acc.x += x0.x; acc.y += x0.y; acc.z += x0.z; acc.w += x0.w;
    acc2.x += x1.x; acc2.y += x1.y; acc2.z += x1.z; acc2.w += x1.w;
  }
  if (e < e1) {
    float4 x0 = Zp[(size_t)csr_src[e] * 128 + 64 + lane];
    acc.x += x0.x; acc.y += x0.y; acc.z += x0.z; acc.w += x0.w;
  }
  float4 bv = ((const float4*)bias)[lane];
  float v0 = fmaxf(acc.x + acc2.x + bv.x, 0.f);
  float v1 = fmaxf(acc.y + acc2.y + bv.y, 0.f);
  float v2 = fmaxf(acc.z + acc2.z + bv.z, 0.f);
  float v3 = fmaxf(acc.w + acc2.w + bv.w, 0.f);
  *(float4*)(stnext + (size_t)row * D + lane * 4) = make_float4(v0, v1, v2, v3);
  ushort h0 = bf16_rn(v0), h1 = bf16_rn(v1), h2 = bf16_rn(v2), h3 = bf16_rn(v3);
  size_t ca = a_addr(row, lane * 4);
  *(ushort4*)&NAh[ca] = make_ushort4(h0, h1, h2, h3);
  *(ushort4*)&NAl[ca] = make_ushort4(
      bf16_rn(v0 - bf16_f(h0)), bf16_rn(v1 - bf16_f(h1)),
      bf16_rn(v2 - bf16_f(h2)), bf16_rn(v3 - bf16_f(h3)));
}

// ---------------------------------------------------------------------------
// k_pi: LINEAR reformulation (validated R5-R7).
// ---------------------------------------------------------------------------
#define PI_LDS_BYTES (TCAP * 64 * 4 + 16 * 64 * 4 + 3 * TCAP * 4 + 17 * 4 + 16 * 4 + 256 * 4)
__global__ __launch_bounds__(64) void k_pi(
    const float* __restrict__ states, float* __restrict__ out,
    const int* __restrict__ variants,
    const int* __restrict__ entP, const int* __restrict__ entPrev,
    const int* __restrict__ entDm, const int* __restrict__ offsG,
    const int* __restrict__ kidxG, const int* __restrict__ tlG,
    const int* __restrict__ cmatG, const int* __restrict__ lastPG,
    const int* __restrict__ lastIG, const int* __restrict__ lastMG,
    const int* __restrict__ cntG) {
  extern __shared__ __align__(16) float smf[];
  float* catb = smf;
  float* S_lds = catb + TCAP * 64;
  int* eP  = (int*)(S_lds + 16 * 64);
  int* ePr = eP + TCAP;
  int* eDm = ePr + TCAP;
  int* offs = eDm + TCAP;
  int* kidx = offs + 17;
  int* tl = kidx + 16;
  int v = blockIdx.x / 12, cgi = blockIdx.x % 12;
  int grp = cgi >> 2;
  int lane = threadIdx.x;
  int cl = (cgi & 3) * 64 + lane;
  int col = cgi * 64 + lane;

  int T = cntG[v * 2 + 0], U = cntG[v * 2 + 1];
  for (int x = lane; x < T; x += 64) {
    eP[x] = entP[v * TCAP + x];
    ePr[x] = entPrev[v * TCAP + x];
    eDm[x] = entDm[v * TCAP + x];
  }
  for (int x = lane; x < 17; x += 64) offs[x] = offsG[v * 17 + x];
  if (lane < 16) kidx[lane] = kidxG[v * 16 + lane];
  for (int x = lane; x < 256; x += 64) tl[x] = tlG[v * 256 + x];
  __syncthreads();

  for (int i = 0; i < L; i++) {
    int kk = kidx[i]; if (kk > NSTATE - 1) kk = NSTATE - 1;
    const float* embS = states + (size_t)kk * N * D;
    int o0 = offs[i], o1 = offs[i + 1];
    if (grp == 0) {
      for (int e = o0; e < o1; e++)
        catb[e * 64 + lane] = embS[(size_t)eP[e] * D + cl];
    } else if (grp == 1) {
      float embA = embS[(size_t)variants[v * L + i] * D + cl];
      for (int e = o0; e < o1; e++) catb[e * 64 + lane] = embA;
    } else {
      for (int e = o0; e < o1; e++) {
        float s = 0.f;
        int b = eDm[e];
        while (b) {
          int q = __ffs(b) - 1; b &= b - 1;
          s += embS[(size_t)tl[i * 16 + q] * D + cl];
        }
        catb[e * 64 + lane] = s;
      }
    }
  }
  for (int e = 0; e < T; e++) {
    int pr = ePr[e];
    if (pr >= 0) catb[e * 64 + lane] += catb[pr * 64 + lane];
  }
  float S[16];
  float Sp = 0.f;
#pragma unroll
  for (int i = 0; i < 16; i++) {
    float a = 0.f;
    for (int e = offs[i]; e < offs[i + 1]; e++) a += catb[e * 64 + lane];
    float s = Sp + a;
#pragma unroll
    for (int j = 0; j < 16; j++)
      if (j < i) s += (float)cmatG[v * 256 + i * 16 + j] * S[j];
    S[i] = s;
    S_lds[i * 64 + lane] = s;
    Sp = s;
  }
  for (int u = 0; u < U; u++) {
    int p = lastPG[v * TCAP + u];
    int li = lastIG[v * TCAP + u];
    int m = lastMG[v * TCAP + u];
    float acc = catb[li * 64 + lane];
    while (m) {
      int q = __ffs(m) - 1; m &= m - 1;
      acc += S_lds[q * 64 + lane];
    }
    atomicAdd(&out[(size_t)p * C + col], acc);
  }
}

// ---------------------------------------------------------------------------
extern "C" void kernel_launch(void* const* d_in, const int* in_sizes, int n_in,
                              void* d_out, int out_size, void* d_ws, size_t ws_size,
                              hipStream_t stream) {
  const float* emb      = (const float*)d_in[0];
  const float* Ws       = (const float*)d_in[1];
  const float* Wn       = (const float*)d_in[2];
  const float* bias     = (const float*)d_in[3];
  const int*   variants = (const int*)d_in[4];
  const int*   adj      = (const int*)d_in[5];
  const int*   ei       = (const int*)d_in[6];
  const int    E        = in_sizes[6] / 2;
  float* out            = (float*)d_out;

  char* base = (char*)d_ws;
  float* states = (float*)base;            base += (size_t)NSTATE * N * D * 4;
  float* Z0     = (float*)base;            base += (size_t)N * 512 * 4;
  float* Z1     = (float*)base;            base += (size_t)N * 512 * 4;
  ushort* WtHi  = (ushort*)base;           base += (size_t)512 * 256 * 2;
  ushort* WtLo  = (ushort*)base;           base += (size_t)512 * 256 * 2;
  ushort* A0h   = (ushort*)base;           base += (size_t)N * D * 2;
  ushort* A0l   = (ushort*)base;           base += (size_t)N * D * 2;
  ushort* A1h   = (ushort*)base;           base += (size_t)N * D * 2;
  ushort* A1l   = (ushort*)base;           base += (size_t)N * D * 2;
  int* row_ptr  = (int*)base;              base += (N + 1) * 4;
  int* fillpos  = (int*)base;              base += N * 4;
  int* csr_src  = (int*)base;              base += (size_t)E * 4;
  int* stepP    = (int*)base;              base += V * L * FCAP * 4;
  int* stepDm   = (int*)base;              base += V * L * FCAP * 4;
  int* stepCnt  = (int*)base;              base += V * L * 4;
  int* hasG     = (int*)base;              base += V * L * 4;
  int* entP     = (int*)base;              base += V * TCAP * 4;
  int* entPrev  = (int*)base;              base += V * TCAP * 4;
  int* entDm    = (int*)base;              base += V * TCAP * 4;
  int* offsG    = (int*)base;              base += V * 17 * 4;
  int* kidxG    = (int*)base;              base += V * 16 * 4;
  int* tlG      = (int*)base;              base += V * 256 * 4;
  int* cmatG    = (int*)base;              base += V * 256 * 4;
  int* lastPG   = (int*)base;              base += V * TCAP * 4;
  int* lastIG   = (int*)base;              base += V * TCAP * 4;
  int* lastMG   = (int*)base;              base += V * TCAP * 4;
  int* cntG     = (int*)base;              base += V * 2 * 4;

  hipFuncSetAttribute((const void*)k_pi,
                      hipFuncAttributeMaxDynamicSharedMemorySize, PI_LDS_BYTES);

  k_init<<<512, 256, 0, stream>>>(emb, Ws, Wn, states, WtHi, WtLo, A0h, A0l,
                                  out, fillpos);
  k_degA<<<128 + V * L, 256, 0, stream>>>(ei, E, fillpos, adj, variants,
                                          stepP, stepDm, stepCnt, hasG, tlG);
  k_scan<<<1, 256, 0, stream>>>(fillpos, row_ptr);
  k_fillB<<<128 + V, 256, 0, stream>>>(ei, E, fillpos, csr_src, stepP, stepDm,
                                       stepCnt, hasG, entP, entPrev, entDm,
                                       offsG, kidxG, cmatG, lastPG, lastIG,
                                       lastMG, cntG);

  // app 0: plain gemm from the k_init-built A0 split
  k_gemm<<<dim3(64, 16), 256, 0, stream>>>(A0h, A0l, WtHi, WtLo, Z0);
  // apps 1..13: fused comb(s-1)+gemm(s)
  float* Zb[2] = {Z0, Z1};
  for (int s = 1; s < NAPP; s++) {
    k_fused<<<dim3(128, 4), 256, 0, stream>>>(
        Zb[(s - 1) & 1], Zb[s & 1], WtHi, WtLo, bias, row_ptr, csr_src,
        states + (size_t)s * N * D);
  }
  // final comb: app 13 -> states[14]
  k_comb<<<N / 4, 256, 0, stream>>>(Zb[(NAPP - 1) & 1], bias, row_ptr, csr_src,
                                    states + (size_t)NAPP * N * D, A1h, A1l);
  k_pi<<<V * 12, 64, PI_LDS_BYTES, stream>>>(states, out, variants, entP,
                                             entPrev, entDm, offsG, kidxG, tlG,
                                             cmatG, lastPG, lastIG, lastMG, cntG);
}

// Round 11
// 384.837 us; speedup vs baseline: 5.4018x; 1.1884x over previous
//
#include <hip/hip_runtime.h>

// Problem constants (fixed by the reference)
#define N 2048
#define D 256
#define C 768          // 3*D
#define V 2
#define L 16
#define NSTATE 15      // S_0..S_14 (step-15 mask provably empty)
#define NAPP 14        // encoder applications
#define TCAP 256       // canonical masked-entry cap per variant (expected ~107)
#define FCAP 64        // follower cap per step (expected ~32)

typedef __attribute__((ext_vector_type(8))) short bf16x8;
typedef __attribute__((ext_vector_type(4))) float f32x4;

__device__ __forceinline__ ushort bf16_rn(float x) {
  unsigned u = __float_as_uint(x);
  u += 0x7FFFu + ((u >> 16) & 1u);
  return (ushort)(u >> 16);
}
__device__ __forceinline__ float bf16_f(ushort h) {
  return __uint_as_float(((unsigned)h) << 16);
}

// Chunk-tiled operand layouts (chunk = 32 rows x 64 k = 2048 ushorts = 4 KB).
__device__ __forceinline__ size_t a_addr(int row, int k) {
  return ((size_t)(row >> 5) * 4 + (k >> 6)) * 2048 + (row & 31) * 64 + (k & 63);
}
__device__ __forceinline__ size_t wt_addr(int n, int k) {
  return ((size_t)(n >> 5) * 4 + (k >> 6)) * 2048 + (n & 31) * 64 + (k & 63);
}

// ---------------------------------------------------------------------------
// k_init: states0 = emb; A0 bf16 split (chunked); Wt=[W_self|W_nbr]^T split
// (chunked); zero out / fillpos.
// ---------------------------------------------------------------------------
__global__ __launch_bounds__(256) void k_init(
    const float* __restrict__ emb, const float* __restrict__ Ws,
    const float* __restrict__ Wn, float* __restrict__ states0,
    ushort* __restrict__ WtHi, ushort* __restrict__ WtLo,
    ushort* __restrict__ A0hi, ushort* __restrict__ A0lo,
    float* __restrict__ out, int* __restrict__ fillpos) {
  size_t i = (size_t)blockIdx.x * 256 + threadIdx.x;
  size_t stride = (size_t)gridDim.x * 256;
  for (size_t x = i; x < (size_t)N * D; x += stride) {
    float v = emb[x];
    states0[x] = v;
    ushort h = bf16_rn(v);
    ushort l = bf16_rn(v - bf16_f(h));
    size_t a = a_addr((int)(x >> 8), (int)(x & 255));
    A0hi[a] = h;
    A0lo[a] = l;
  }
  for (size_t x = i; x < (size_t)512 * 256; x += stride) {
    int n = (int)(x >> 8), k = (int)(x & 255);
    float v = (n < 256) ? Ws[(size_t)k * 256 + n] : Wn[(size_t)k * 256 + (n - 256)];
    ushort h = bf16_rn(v);
    size_t a = wt_addr(n, k);
    WtHi[a] = h;
    WtLo[a] = bf16_rn(v - bf16_f(h));
  }
  for (size_t x = i; x < (size_t)N * C; x += stride) out[x] = 0.f;
  for (size_t x = i; x < N; x += stride) fillpos[x] = 0;
}

// ---------------------------------------------------------------------------
// k_degA: fused k_deg (blocks 0..127) + k_metaA (blocks 128..159).
// ---------------------------------------------------------------------------
__global__ __launch_bounds__(256) void k_degA(
    const int* __restrict__ ei, int E, int* __restrict__ fillpos,
    const int* __restrict__ adj, const int* __restrict__ variants,
    int* __restrict__ stepP, int* __restrict__ stepDm,
    int* __restrict__ stepCnt, int* __restrict__ hasG, int* __restrict__ tlG) {
  __shared__ int tl_sh[16];
  __shared__ int foll[FCAP], fbits[FCAP];
  __shared__ int sh_tc, sh_fcnt, sh_ecnt;
  int t = threadIdx.x;
  if (blockIdx.x < 128) {
    for (int e = blockIdx.x * 256 + t; e < E; e += 128 * 256)
      atomicAdd(&fillpos[ei[E + e]], 1);
    return;
  }
  int vi = blockIdx.x - 128;
  int v = vi / L, i = vi % L;
  int a = variants[vi];
  if (t == 0) {
    int cnt = 0;
    for (int j = i + 1; j < L; j++) {
      int x = variants[v * L + j];
      bool dup = false;
      for (int q = 0; q < cnt; q++) if (tl_sh[q] == x) dup = true;
      if (!dup) tl_sh[cnt++] = x;
    }
    sh_tc = cnt;
    sh_fcnt = 0;
    sh_ecnt = 0;
    for (int q = 0; q < cnt; q++) tlG[vi * 16 + q] = tl_sh[q];
  }
  __syncthreads();
  for (int p = t; p < N; p += 256) {
    if (adj[(size_t)a * N + p] != 0) {
      int f = atomicAdd(&sh_fcnt, 1);
      if (f < FCAP) foll[f] = p;
    }
  }
  __syncthreads();
  int fc = sh_fcnt < FCAP ? sh_fcnt : FCAP;
  int tc = sh_tc;
  for (int x = t; x < fc; x += 256) fbits[x] = 0;
  __syncthreads();
  for (int x = t; x < fc * tc; x += 256) {
    int fi = x / tc, q = x - fi * tc;
    if (adj[(size_t)foll[fi] * N + tl_sh[q]] != 0) atomicOr(&fbits[fi], 1 << q);
  }
  __syncthreads();
  for (int fi = t; fi < fc; fi += 256) {
    int bits = fbits[fi];
    if (bits) {
      int e = atomicAdd(&sh_ecnt, 1);
      stepP[vi * FCAP + e] = foll[fi];
      stepDm[vi * FCAP + e] = bits;
    }
  }
  __syncthreads();
  if (t == 0) {
    stepCnt[vi] = sh_ecnt;
    hasG[vi] = (sh_fcnt > 0);
  }
}

// ---------------------------------------------------------------------------
// k_scan: exclusive prefix over degrees -> row_ptr; resets fillpos to starts.
// ---------------------------------------------------------------------------
__global__ __launch_bounds__(256) void k_scan(int* __restrict__ fillpos,
                                              int* __restrict__ row_ptr) {
  __shared__ int part[256];
  __shared__ int base[257];
  int t = threadIdx.x;
  int v[8];
  int s = 0;
  for (int j = 0; j < 8; j++) { v[j] = fillpos[t * 8 + j]; s += v[j]; }
  part[t] = s;
  __syncthreads();
  if (t == 0) {
    int acc = 0;
    for (int q = 0; q < 256; q++) { base[q] = acc; acc += part[q]; }
    base[256] = acc;
  }
  __syncthreads();
  int acc = base[t];
  for (int j = 0; j < 8; j++) {
    row_ptr[t * 8 + j] = acc;
    fillpos[t * 8 + j] = acc;
    acc += v[j];
  }
  if (t == 255) row_ptr[N] = base[256];
}

// ---------------------------------------------------------------------------
// k_fillB: fused k_fill (blocks 0..127) + k_metaB (blocks 128..128+V-1).
// ---------------------------------------------------------------------------
__global__ __launch_bounds__(256) void k_fillB(
    const int* __restrict__ ei, int E, int* __restrict__ fillpos,
    int* __restrict__ csr_src,
    const int* __restrict__ stepP, const int* __restrict__ stepDm,
    const int* __restrict__ stepCnt, const int* __restrict__ hasG,
    int* __restrict__ entP, int* __restrict__ entPrev, int* __restrict__ entDm,
    int* __restrict__ offsG, int* __restrict__ kidxG, int* __restrict__ cmatG,
    int* __restrict__ lastPG, int* __restrict__ lastIG, int* __restrict__ lastMG,
    int* __restrict__ cntG) {
  __shared__ int pmask[N];
  __shared__ int sP[16][FCAP];
  __shared__ int sDm[16][FCAP];
  __shared__ int cnt[16], offs[17];
  __shared__ int cmat_sh[256];
  __shared__ int sh_u;
  int t = threadIdx.x;
  if (blockIdx.x < 128) {
    for (int e = blockIdx.x * 256 + t; e < E; e += 128 * 256) {
      int dst = ei[E + e];
      int pos = atomicAdd(&fillpos[dst], 1);
      csr_src[pos] = ei[e];
    }
    return;
  }
  int v = blockIdx.x - 128;
  for (int p = t; p < N; p += 256) pmask[p] = 0;
  for (int x = t; x < 256; x += 256) cmat_sh[x] = 0;
  if (t < 16) cnt[t] = stepCnt[v * L + t];
  if (t == 0) sh_u = 0;
  __syncthreads();
  if (t == 0) {
    int acc = 0;
    for (int i = 0; i < 16; i++) {
      offs[i] = acc < TCAP ? acc : TCAP;
      acc += cnt[i];
    }
    offs[16] = acc < TCAP ? acc : TCAP;
    cntG[v * 2 + 0] = offs[16];
    int k = 0;
    for (int i = 0; i < L; i++) {
      kidxG[v * 16 + i] = k;
      if (hasG[v * L + i]) k++;
    }
  }
  for (int x = t; x < 16 * FCAP; x += 256) {
    int i = x >> 6, f = x & 63;
    if (f < stepCnt[v * L + i]) {
      int p = stepP[(v * L + i) * FCAP + f];
      sP[i][f] = p;
      sDm[i][f] = stepDm[(v * L + i) * FCAP + f];
      atomicOr(&pmask[p], 1 << i);
    }
  }
  __syncthreads();
  for (int x = t; x < 16 * FCAP; x += 256) {
    int i = x >> 6, f = x & 63;
    if (f < cnt[i]) {
      int e = offs[i] + f;
      if (e < TCAP) {
        int p = sP[i][f];
        entP[v * TCAP + e] = p;
        entDm[v * TCAP + e] = sDm[i][f];
        int m = pmask[p] & ((1 << i) - 1);
        int prev = -1;
        if (m) {
          int j = 31 - __clz(m);
          int cj = cnt[j];
          for (int f2 = 0; f2 < cj; f2++)
            if (sP[j][f2] == p) { prev = offs[j] + f2; break; }
        }
        entPrev[v * TCAP + e] = prev;
      }
    }
  }
  __syncthreads();
  for (int p = t; p < N; p += 256) {
    int m = pmask[p];
    if (m) {
      int u = atomicAdd(&sh_u, 1);
      int j = 31 - __clz(m);
      int li = -1;
      int cj = cnt[j];
      for (int f2 = 0; f2 < cj; f2++)
        if (sP[j][f2] == p) { li = offs[j] + f2; break; }
      lastPG[v * TCAP + u] = p;
      lastIG[v * TCAP + u] = li;
      lastMG[v * TCAP + u] = m;
      int mm = m;
      while (mm) {
        int bi = __ffs(mm) - 1; mm &= mm - 1;
        int m2 = m & ((1 << bi) - 1);
        while (m2) {
          int bj = __ffs(m2) - 1; m2 &= m2 - 1;
          atomicAdd(&cmat_sh[bi * 16 + bj], 1);
        }
      }
    }
  }
  __syncthreads();
  if (t == 0) cntG[v * 2 + 1] = sh_u;
  for (int x = t; x < 256; x += 256) cmatG[v * 256 + x] = cmat_sh[x];
  for (int x = t; x < 17; x += 256) offsG[v * 17 + x] = offs[x];
}

// ---------------------------------------------------------------------------
// k_gemm: Z = A @ [W_self|W_nbr]  (M=2048, K=256, N=512), bf16 3-product
// split, fp32 accum, LDS double-buffered.  (R7-validated; app 0 only)
// ---------------------------------------------------------------------------
__global__ __launch_bounds__(256) void k_gemm(
    const ushort* __restrict__ Ah, const ushort* __restrict__ Al,
    const ushort* __restrict__ Wh_g, const ushort* __restrict__ Wl_g,
    float* __restrict__ Z) {
  __shared__ __align__(16) ushort Ash[2][32][72], Asl[2][32][72];
  __shared__ __align__(16) ushort Wsh[2][32][72], Wsl[2][32][72];
  const int tid = threadIdx.x, wave = tid >> 6, lane = tid & 63;
  const int quad = lane >> 4, l16 = lane & 15;
  const int wr = wave >> 1, wc = wave & 1;
  const int mb = blockIdx.x, nb = blockIdx.y;
  const int sr = tid >> 3, sc = (tid & 7) * 8;

  f32x4 acc = {0.f, 0.f, 0.f, 0.f};
  size_t abase = (size_t)mb * 4 * 2048 + (size_t)tid * 8;
  size_t wbase = (size_t)nb * 4 * 2048 + (size_t)tid * 8;
  {
    uint4 ra  = *(const uint4*)&Ah[abase];
    uint4 rl  = *(const uint4*)&Al[abase];
    uint4 rwh = *(const uint4*)&Wh_g[wbase];
    uint4 rwl = *(const uint4*)&Wl_g[wbase];
    *(uint4*)&Ash[0][sr][sc] = ra;
    *(uint4*)&Asl[0][sr][sc] = rl;
    *(uint4*)&Wsh[0][sr][sc] = rwh;
    *(uint4*)&Wsl[0][sr][sc] = rwl;
  }
  __syncthreads();
#pragma unroll
  for (int c = 0; c < 4; c++) {
    const int rb = c & 1;
    uint4 ra, rl, rwh, rwl;
    if (c < 3) {
      size_t o = (size_t)(c + 1) * 2048;
      ra  = *(const uint4*)&Ah[abase + o];
      rl  = *(const uint4*)&Al[abase + o];
      rwh = *(const uint4*)&Wh_g[wbase + o];
      rwl = *(const uint4*)&Wl_g[wbase + o];
    }
#pragma unroll
    for (int kf = 0; kf < 2; kf++) {
      int ko = kf * 32 + quad * 8;
      bf16x8 a_h = *(const bf16x8*)&Ash[rb][wr * 16 + l16][ko];
      bf16x8 a_l = *(const bf16x8*)&Asl[rb][wr * 16 + l16][ko];
      bf16x8 w_h = *(const bf16x8*)&Wsh[rb][wc * 16 + l16][ko];
      bf16x8 w_l = *(const bf16x8*)&Wsl[rb][wc * 16 + l16][ko];
      acc = __builtin_amdgcn_mfma_f32_16x16x32_bf16(a_h, w_h, acc, 0, 0, 0);
      acc = __builtin_amdgcn_mfma_f32_16x16x32_bf16(a_h, w_l, acc, 0, 0, 0);
      acc = __builtin_amdgcn_mfma_f32_16x16x32_bf16(a_l, w_h, acc, 0, 0, 0);
    }
    if (c < 3) {
      const int wb = rb ^ 1;
      *(uint4*)&Ash[wb][sr][sc] = ra;
      *(uint4*)&Asl[wb][sr][sc] = rl;
      *(uint4*)&Wsh[wb][sr][sc] = rwh;
      *(uint4*)&Wsl[wb][sr][sc] = rwl;
      __syncthreads();
    }
  }
  int col = nb * 32 + wc * 16 + l16;
  int row0 = mb * 32 + wr * 16 + quad * 4;
#pragma unroll
  for (int r = 0; r < 4; r++)
    Z[(size_t)(row0 + r) * 512 + col] = acc[r];
}

// ---------------------------------------------------------------------------
// k_fused: comb(s-1) + gemm(s), ZERO gather replication.  Grid (256,1),
// 512 threads; block = 8 rows x ALL 512 cols.
// Phase A: each wave combs ONE row from Zprev (R7 body), writes states[s],
// bf16-splits into LDS A (9 rows: 8 real + 1 zero for MFMA lanes 8..15).
// Phase B: stream W in 4 K-pieces (512 cols x 64 k, 128 KB) through LDS;
// wave w owns cols w*64..+64 (4 n-tiles).  MFMA M=16 with 8 zero rows.
// LDS total 156960 B -> 1 block/CU by design.
// ---------------------------------------------------------------------------
#define FU_A 2376           // ushorts per A half (9 rows x 264)
#define FU_W 36864          // ushorts per W half (512 x 72)
#define FU_LDS_BYTES ((2 * FU_A + 2 * FU_W) * 2)
__global__ __launch_bounds__(512) void k_fused(
    const float* __restrict__ Zprev, float* __restrict__ Znext,
    const ushort* __restrict__ WtHi, const ushort* __restrict__ WtLo,
    const float* __restrict__ bias, const int* __restrict__ row_ptr,
    const int* __restrict__ csr_src, float* __restrict__ stthis) {
  extern __shared__ __align__(16) ushort sm[];
  ushort* Ash = sm;               // [9][264]
  ushort* Asl = sm + FU_A;
  ushort* Wsh = sm + 2 * FU_A;    // [512][72]
  ushort* Wsl = Wsh + FU_W;
  const int tid = threadIdx.x, wave = tid >> 6, lane = tid & 63;
  const int quad = lane >> 4, l16 = lane & 15;
  const int r0 = blockIdx.x * 8;

  // ---- phase A: comb row r0+wave (one row per wave) ----
  {
    int row = r0 + wave;
    const float4* Zp = (const float4*)Zprev;
    float4 acc = Zp[(size_t)row * 128 + lane];         // Z1 self
    float4 acc2 = {0.f, 0.f, 0.f, 0.f};
    int e0 = row_ptr[row], e1 = row_ptr[row + 1];
    int e = e0;
    for (; e + 1 < e1; e += 2) {
      int s0 = csr_src[e], s1 = csr_src[e + 1];
      float4 x0 = Zp[(size_t)s0 * 128 + 64 + lane];
      float4 x1 = Zp[(size_t)s1 * 128 + 64 + lane];
      acc.x += x0.x; acc.y += x0.y; acc.z += x0.z; acc.w += x0.w;
      acc2.x += x1.x; acc2.y += x1.y; acc2.z += x1.z; acc2.w += x1.w;
    }
    if (e < e1) {
      float4 x0 = Zp[(size_t)csr_src[e] * 128 + 64 + lane];
      acc.x += x0.x; acc.y += x0.y; acc.z += x0.z; acc.w += x0.w;
    }
    float4 bv = ((const float4*)bias)[lane];
    float v0 = fmaxf(acc.x + acc2.x + bv.x, 0.f);
    float v1 = fmaxf(acc.y + acc2.y + bv.y, 0.f);
    float v2 = fmaxf(acc.z + acc2.z + bv.z, 0.f);
    float v3 = fmaxf(acc.w + acc2.w + bv.w, 0.f);
    *(float4*)(stthis + (size_t)row * D + lane * 4) = make_float4(v0, v1, v2, v3);
    ushort h0 = bf16_rn(v0), h1 = bf16_rn(v1), h2 = bf16_rn(v2), h3 = bf16_rn(v3);
    *(ushort4*)&Ash[wave * 264 + lane * 4] = make_ushort4(h0, h1, h2, h3);
    *(ushort4*)&Asl[wave * 264 + lane * 4] = make_ushort4(
        bf16_rn(v0 - bf16_f(h0)), bf16_rn(v1 - bf16_f(h1)),
        bf16_rn(v2 - bf16_f(h2)), bf16_rn(v3 - bf16_f(h3)));
  }
  // zero row 8 (MFMA lanes l16 >= 8 read this)
  for (int x = tid; x < 264; x += 512) {
    Ash[8 * 264 + x] = 0;
    Asl[8 * 264 + x] = 0;
  }

  // ---- phase B: Znext rows r0..r0+7 (all 512 cols) ----
  f32x4 acc[4] = {};
  const int ar = (l16 < 8 ? l16 : 8) * 264;
#pragma unroll
  for (int kc = 0; kc < 4; kc++) {
    __syncthreads();   // A ready (kc=0) / prior W piece reads done (kc>0)
    // load W piece kc: 16 chunks of 2048 ushorts each (hi + lo)
#pragma unroll
    for (int it = 0; it < 8; it++) {
      int x = tid * 8 + it * 4096;
      int ni = x >> 11, j = x & 2047;
      int nrow = ni * 32 + (j >> 6), kk = j & 63;
      size_t g = (size_t)(ni * 4 + kc) * 2048 + j;
      *(uint4*)&Wsh[nrow * 72 + kk] = *(const uint4*)&WtHi[g];
      *(uint4*)&Wsl[nrow * 72 + kk] = *(const uint4*)&WtLo[g];
    }
    __syncthreads();
#pragma unroll
    for (int kf = 0; kf < 2; kf++) {
      int ao = kc * 64 + kf * 32 + quad * 8;
      int wo = kf * 32 + quad * 8;
      bf16x8 a_h = *(const bf16x8*)&Ash[ar + ao];
      bf16x8 a_l = *(const bf16x8*)&Asl[ar + ao];
#pragma unroll
      for (int nt = 0; nt < 4; nt++) {
        int n = wave * 64 + nt * 16 + l16;
        bf16x8 w_h = *(const bf16x8*)&Wsh[n * 72 + wo];
        bf16x8 w_l = *(const bf16x8*)&Wsl[n * 72 + wo];
        acc[nt] = __builtin_amdgcn_mfma_f32_16x16x32_bf16(a_h, w_h, acc[nt], 0, 0, 0);
        acc[nt] = __builtin_amdgcn_mfma_f32_16x16x32_bf16(a_h, w_l, acc[nt], 0, 0, 0);
        acc[nt] = __builtin_amdgcn_mfma_f32_16x16x32_bf16(a_l, w_h, acc[nt], 0, 0, 0);
      }
    }
  }
#pragma unroll
  for (int nt = 0; nt < 4; nt++) {
    int col = wave * 64 + nt * 16 + l16;
#pragma unroll
    for (int r = 0; r < 4; r++) {
      int row = quad * 4 + r;
      if (row < 8)
        Znext[(size_t)(r0 + row) * 512 + col] = acc[nt][r];
    }
  }
}

// ---------------------------------------------------------------------------
// k_comb: final comb (app 13 -> states[14]).  R7-validated.
// ---------------------------------------------------------------------------
__global__ __launch_bounds__(256) void k_comb(
    const float* __restrict__ Z, const float* __restrict__ bias,
    const int* __restrict__ row_ptr, const int* __restrict__ csr_src,
    float* __restrict__ stnext) {
  int row = blockIdx.x * 4 + (threadIdx.x >> 6);
  int lane = threadIdx.x & 63;
  const float4* Zp = (const float4*)Z;
  float4 acc = Zp[(size_t)row * 128 + lane];
  float4 acc2 = {0.f, 0.f, 0.f, 0.f};
  int e0 = row_ptr[row], e1 = row_ptr[row + 1];
  int e = e0;
  for (; e + 1 < e1; e += 2) {
    int s0 = csr_src[e], s1 = csr_src[e + 1];
    float4 x0 = Zp[(size_t)s0 * 128 + 64 + lane];
    float4 x1 = Zp[(size_t)s1 * 128 + 64 + lane];
    acc.x += x0.x; acc.y += x0.y; acc.z += x0.z; acc.w += x0.w;
    acc2.x += x1.x; acc2.y += x1.y; acc2.z += x1.z; acc2.w += x1.w;
  }
  if (e < e1) {
    float4 x0 = Zp[(size_t)csr_src[e] * 128 + 64 + lane];
    acc.x += x0.x; acc.y += x0.y; acc.z += x0.z; acc.w += x0.w;
  }
  float4 bv = ((const float4*)bias)[lane];
  float v0 = fmaxf(acc.x + acc2.x + bv.x, 0.f);
  float v1 = fmaxf(acc.y + acc2.y + bv.y, 0.f);
  float v2 = fmaxf(acc.z + acc2.z + bv.z, 0.f);
  float v3 = fmaxf(acc.w + acc2.w + bv.w, 0.f);
  *(float4*)(stnext + (size_t)row * D + lane * 4) = make_float4(v0, v1, v2, v3);
}

// ---------------------------------------------------------------------------
// k_pi: LINEAR reformulation (validated R5-R7).
// ---------------------------------------------------------------------------
#define PI_LDS_BYTES (TCAP * 64 * 4 + 16 * 64 * 4 + 3 * TCAP * 4 + 17 * 4 + 16 * 4 + 256 * 4)
__global__ __launch_bounds__(64) void k_pi(
    const float* __restrict__ states, float* __restrict__ out,
    const int* __restrict__ variants,
    const int* __restrict__ entP, const int* __restrict__ entPrev,
    const int* __restrict__ entDm, const int* __restrict__ offsG,
    const int* __restrict__ kidxG, const int* __restrict__ tlG,
    const int* __restrict__ cmatG, const int* __restrict__ lastPG,
    const int* __restrict__ lastIG, const int* __restrict__ lastMG,
    const int* __restrict__ cntG) {
  extern __shared__ __align__(16) float smf[];
  float* catb = smf;
  float* S_lds = catb + TCAP * 64;
  int* eP  = (int*)(S_lds + 16 * 64);
  int* ePr = eP + TCAP;
  int* eDm = ePr + TCAP;
  int* offs = eDm + TCAP;
  int* kidx = offs + 17;
  int* tl = kidx + 16;
  int v = blockIdx.x / 12, cgi = blockIdx.x % 12;
  int grp = cgi >> 2;
  int lane = threadIdx.x;
  int cl = (cgi & 3) * 64 + lane;
  int col = cgi * 64 + lane;

  int T = cntG[v * 2 + 0], U = cntG[v * 2 + 1];
  for (int x = lane; x < T; x += 64) {
    eP[x] = entP[v * TCAP + x];
    ePr[x] = entPrev[v * TCAP + x];
    eDm[x] = entDm[v * TCAP + x];
  }
  for (int x = lane; x < 17; x += 64) offs[x] = offsG[v * 17 + x];
  if (lane < 16) kidx[lane] = kidxG[v * 16 + lane];
  for (int x = lane; x < 256; x += 64) tl[x] = tlG[v * 256 + x];
  __syncthreads();

  for (int i = 0; i < L; i++) {
    int kk = kidx[i]; if (kk > NSTATE - 1) kk = NSTATE - 1;
    const float* embS = states + (size_t)kk * N * D;
    int o0 = offs[i], o1 = offs[i + 1];
    if (grp == 0) {
      for (int e = o0; e < o1; e++)
        catb[e * 64 + lane] = embS[(size_t)eP[e] * D + cl];
    } else if (grp == 1) {
      float embA = embS[(size_t)variants[v * L + i] * D + cl];
      for (int e = o0; e < o1; e++) catb[e * 64 + lane] = embA;
    } else {
      for (int e = o0; e < o1; e++) {
        float s = 0.f;
        int b = eDm[e];
        while (b) {
          int q = __ffs(b) - 1; b &= b - 1;
          s += embS[(size_t)tl[i * 16 + q] * D + cl];
        }
        catb[e * 64 + lane] = s;
      }
    }
  }
  for (int e = 0; e < T; e++) {
    int pr = ePr[e];
    if (pr >= 0) catb[e * 64 + lane] += catb[pr * 64 + lane];
  }
  float S[16];
  float Sp = 0.f;
#pragma unroll
  for (int i = 0; i < 16; i++) {
    float a = 0.f;
    for (int e = offs[i]; e < offs[i + 1]; e++) a += catb[e * 64 + lane];
    float s = Sp + a;
#pragma unroll
    for (int j = 0; j < 16; j++)
      if (j < i) s += (float)cmatG[v * 256 + i * 16 + j] * S[j];
    S[i] = s;
    S_lds[i * 64 + lane] = s;
    Sp = s;
  }
  for (int u = 0; u < U; u++) {
    int p = lastPG[v * TCAP + u];
    int li = lastIG[v * TCAP + u];
    int m = lastMG[v * TCAP + u];
    float acc = catb[li * 64 + lane];
    while (m) {
      int q = __ffs(m) - 1; m &= m - 1;
      acc += S_lds[q * 64 + lane];
    }
    atomicAdd(&out[(size_t)p * C + col], acc);
  }
}

// ---------------------------------------------------------------------------
extern "C" void kernel_launch(void* const* d_in, const int* in_sizes, int n_in,
                              void* d_out, int out_size, void* d_ws, size_t ws_size,
                              hipStream_t stream) {
  const float* emb      = (const float*)d_in[0];
  const float* Ws       = (const float*)d_in[1];
  const float* Wn       = (const float*)d_in[2];
  const float* bias     = (const float*)d_in[3];
  const int*   variants = (const int*)d_in[4];
  const int*   adj      = (const int*)d_in[5];
  const int*   ei       = (const int*)d_in[6];
  const int    E        = in_sizes[6] / 2;
  float* out            = (float*)d_out;

  char* base = (char*)d_ws;
  float* states = (float*)base;            base += (size_t)NSTATE * N * D * 4;
  float* Z0     = (float*)base;            base += (size_t)N * 512 * 4;
  float* Z1     = (float*)base;            base += (size_t)N * 512 * 4;
  ushort* WtHi  = (ushort*)base;           base += (size_t)512 * 256 * 2;
  ushort* WtLo  = (ushort*)base;           base += (size_t)512 * 256 * 2;
  ushort* A0h   = (ushort*)base;           base += (size_t)N * D * 2;
  ushort* A0l   = (ushort*)base;           base += (size_t)N * D * 2;
  int* row_ptr  = (int*)base;              base += (N + 1) * 4;
  int* fillpos  = (int*)base;              base += N * 4;
  int* csr_src  = (int*)base;              base += (size_t)E * 4;
  int* stepP    = (int*)base;              base += V * L * FCAP * 4;
  int* stepDm   = (int*)base;              base += V * L * FCAP * 4;
  int* stepCnt  = (int*)base;              base += V * L * 4;
  int* hasG     = (int*)base;              base += V * L * 4;
  int* entP     = (int*)base;              base += V * TCAP * 4;
  int* entPrev  = (int*)base;              base += V * TCAP * 4;
  int* entDm    = (int*)base;              base += V * TCAP * 4;
  int* offsG    = (int*)base;              base += V * 17 * 4;
  int* kidxG    = (int*)base;              base += V * 16 * 4;
  int* tlG      = (int*)base;              base += V * 256 * 4;
  int* cmatG    = (int*)base;              base += V * 256 * 4;
  int* lastPG   = (int*)base;              base += V * TCAP * 4;
  int* lastIG   = (int*)base;              base += V * TCAP * 4;
  int* lastMG   = (int*)base;              base += V * TCAP * 4;
  int* cntG     = (int*)base;              base += V * 2 * 4;

  hipFuncSetAttribute((const void*)k_pi,
                      hipFuncAttributeMaxDynamicSharedMemorySize, PI_LDS_BYTES);
  hipFuncSetAttribute((const void*)k_fused,
                      hipFuncAttributeMaxDynamicSharedMemorySize, FU_LDS_BYTES);

  k_init<<<512, 256, 0, stream>>>(emb, Ws, Wn, states, WtHi, WtLo, A0h, A0l,
                                  out, fillpos);
  k_degA<<<128 + V * L, 256, 0, stream>>>(ei, E, fillpos, adj, variants,
                                          stepP, stepDm, stepCnt, hasG, tlG);
  k_scan<<<1, 256, 0, stream>>>(fillpos, row_ptr);
  k_fillB<<<128 + V, 256, 0, stream>>>(ei, E, fillpos, csr_src, stepP, stepDm,
                                       stepCnt, hasG, entP, entPrev, entDm,
                                       offsG, kidxG, cmatG, lastPG, lastIG,
                                       lastMG, cntG);

  // app 0: plain gemm from the k_init-built A0 split
  k_gemm<<<dim3(64, 16), 256, 0, stream>>>(A0h, A0l, WtHi, WtLo, Z0);
  // apps 1..13: fused comb(s-1)+gemm(s), no gather replication
  float* Zb[2] = {Z0, Z1};
  for (int s = 1; s < NAPP; s++) {
    k_fused<<<256, 512, FU_LDS_BYTES, stream>>>(
        Zb[(s - 1) & 1], Zb[s & 1], WtHi, WtLo, bias, row_ptr, csr_src,
        states + (size_t)s * N * D);
  }
  // final comb: app 13 -> states[14]
  k_comb<<<N / 4, 256, 0, stream>>>(Zb[(NAPP - 1) & 1], bias, row_ptr, csr_src,
                                    states + (size_t)NAPP * N * D);
  k_pi<<<V * 12, 64, PI_LDS_BYTES, stream>>>(states, out, variants, entP,
                                             entPrev, entDm, offsG, kidxG, tlG,
                                             cmatG, lastPG, lastIG, lastMG, cntG);
}